// Round 9
// baseline (458.669 us; speedup 1.0000x reference)
//
#include <hip/hip_runtime.h>
#include <hip/hip_cooperative_groups.h>

namespace cg = cooperative_groups;

#define D 64
#define NPB 128              // nodes per bucket (dstLocal: 7 bits)
#define NPB_SHIFT 7
#define MAXB 1024            // bound on bucket count B = ceil(N/NPB)
#define BT 512               // block threads (8 waves)
#define GRIDC 768            // cooperative grid: 3 blocks/CU x 256 CU
#define CHUNK_MAX 1568       // max edges per scatter chunk (E/GRIDC for 1.2M)
#define SCQ 4                // per-thread reg-staged edges (SCQ*BT >= CHUNK_MAX)
#define CAPB 2560            // fixed per-bucket capacity in adjB (mean 1534)
#define GQ 5                 // per-thread reg-staged bucket entries (GQ*BT >= CAPB)
#define MAGIC 0x5CA77E12

// round-to-nearest-even fp32 -> bf16 (values are finite/normal here)
__device__ inline unsigned f2bf(float f) {
    unsigned u = __float_as_uint(f);
    return (u + 0x7FFFu + ((u >> 16) & 1u)) >> 16;
}

// ---------------------------------------------------------------------------
// shared-LDS structs (coop kernel uses a union of all three phases)
// ---------------------------------------------------------------------------
struct GmLds { float th[D * D]; float at[D][68]; };                    // 33.8KB
struct ScLds {
    int lc[MAXB]; int lpre[MAXB]; int lbase[MAXB]; int lfill[MAXB];
    int wsum[8]; int wexc[8];
    unsigned short sb[CHUNK_MAX]; int2 stage[CHUNK_MAX];
};                                                                      // 32.1KB
struct GaLds { int cnt[NPB]; int pre[NPB]; int fill[NPB]; int sOvf;
               int2 ladj[CAPB]; };                                      // 22.0KB

// ---------------------------------------------------------------------------
// gemm phase bodies (512 threads, 64-row tile, 2 rows x 4 cols per thread;
// r3-verified body). theta staged once; at[] restaged per tile.
// ---------------------------------------------------------------------------
__device__ inline void gemm_theta(GmLds& S, const float* __restrict__ theta, int t) {
#pragma unroll
    for (int i = 0; i < 2; ++i)
        ((float4*)S.th)[t + i * BT] = ((const float4*)theta)[t + i * BT];
}

__device__ inline void gemm_tile(GmLds& S, const float* __restrict__ A,
                                 unsigned short* __restrict__ proj16,
                                 int rowBase, int N, int t) {
#pragma unroll
    for (int i = 0; i < 2; ++i) {
        int f = t + i * BT;
        int row = f >> 4;
        int kv = f & 15;
        float4 v = make_float4(0.f, 0.f, 0.f, 0.f);
        if (rowBase + row < N) v = *(const float4*)&A[(size_t)(rowBase + row) * D + kv * 4];
        S.at[kv * 4 + 0][row] = v.x;
        S.at[kv * 4 + 1][row] = v.y;
        S.at[kv * 4 + 2][row] = v.z;
        S.at[kv * 4 + 3][row] = v.w;
    }
    __syncthreads();

    int c0 = (t & 15) * 4;
    int r0 = (t >> 4) * 2;
    float4 a0 = make_float4(0.f, 0.f, 0.f, 0.f);
    float4 a1 = a0;
#pragma unroll 16
    for (int k = 0; k < D; ++k) {
        float4 bv = *(const float4*)&S.th[k * D + c0];
        float x0 = S.at[k][r0];
        float x1 = S.at[k][r0 + 1];
        a0.x += x0 * bv.x; a0.y += x0 * bv.y; a0.z += x0 * bv.z; a0.w += x0 * bv.w;
        a1.x += x1 * bv.x; a1.y += x1 * bv.y; a1.z += x1 * bv.z; a1.w += x1 * bv.w;
    }
    int r = rowBase + r0;
    if (r < N) {
        unsigned lo = f2bf(a0.x) | (f2bf(a0.y) << 16);
        unsigned hi = f2bf(a0.z) | (f2bf(a0.w) << 16);
        *(uint2*)&proj16[(size_t)r * D + c0] = make_uint2(lo, hi);
    }
    if (r + 1 < N) {
        unsigned lo = f2bf(a1.x) | (f2bf(a1.y) << 16);
        unsigned hi = f2bf(a1.z) | (f2bf(a1.w) << 16);
        *(uint2*)&proj16[(size_t)(r + 1) * D + c0] = make_uint2(lo, hi);
    }
}

// ---------------------------------------------------------------------------
// scatter phase body (r8-verified): reg-stage edges -> LDS chunk histogram ->
// shfl wave-scan excl prefix -> reserve per-bucket ranges from cursors ->
// LDS counting sort -> coalesced write-out. Overflow past CAPB -> ovf.
// Packing: x = src | dstLocal<<20, y = w bits. No returns (coop-safe).
// ---------------------------------------------------------------------------
__device__ inline void scatter_body(ScLds& S,
        const int* __restrict__ src, const int* __restrict__ dst,
        const float* __restrict__ w, int* __restrict__ cursor,
        int* __restrict__ ovfCnt, int4* __restrict__ ovf,
        int2* __restrict__ adjB, int E, int B, int bid, int nblk) {
    int t = threadIdx.x;
    int chunk = (E + nblk - 1) / nblk;            // <= CHUNK_MAX by host guard
    int lo = bid * chunk, hi = min(lo + chunk, E);
    int n = hi - lo;
    if (n <= 0) return;                           // block-uniform skip

    for (int i = t; i < MAXB; i += BT) { S.lc[i] = 0; S.lfill[i] = 0; }

    int rd[SCQ]; int rs[SCQ]; float rw[SCQ];
#pragma unroll
    for (int q = 0; q < SCQ; ++q) {
        int e = lo + t + q * BT;
        bool v = e < hi;
        rd[q] = v ? dst[e] : -1;
        rs[q] = v ? src[e] : 0;
        rw[q] = v ? w[e] : 0.f;
    }
    __syncthreads();

#pragma unroll
    for (int q = 0; q < SCQ; ++q)
        if (rd[q] >= 0) atomicAdd(&S.lc[rd[q] >> NPB_SHIFT], 1);
    __syncthreads();

    // exclusive scan of lc[0..MAXB): 2 counts/thread, shfl wave-scan + combine
    int s0 = S.lc[2 * t], s1 = S.lc[2 * t + 1];
    int tsum = s0 + s1;
    int lane = t & 63, wid = t >> 6;
    int v = tsum;
#pragma unroll
    for (int off = 1; off < 64; off <<= 1) {
        int u = __shfl_up(v, off, 64);
        if (lane >= off) v += u;
    }
    if (lane == 63) S.wsum[wid] = v;
    __syncthreads();
    if (t < 8) {
        int acc = 0;
        for (int i = 0; i < t; ++i) acc += S.wsum[i];
        S.wexc[t] = acc;
    }
    __syncthreads();
    int base = S.wexc[wid] + (v - tsum);
    S.lpre[2 * t] = base;
    S.lpre[2 * t + 1] = base + s0;
    __syncthreads();

    for (int i = t; i < B; i += BT) {
        int c = S.lc[i];
        S.lbase[i] = c ? atomicAdd(&cursor[i], c) : 0;
    }
    __syncthreads();

#pragma unroll
    for (int q = 0; q < SCQ; ++q) {
        int d = rd[q];
        if (d >= 0) {
            int bkt = d >> NPB_SHIFT;
            int i = S.lpre[bkt] + atomicAdd(&S.lfill[bkt], 1);
            S.stage[i] = make_int2(rs[q] | ((d & (NPB - 1)) << 20),
                                   __float_as_int(rw[q]));
            S.sb[i] = (unsigned short)bkt;
        }
    }
    __syncthreads();

    for (int i = t; i < n; i += BT) {
        int bkt = S.sb[i];
        int2 vv = S.stage[i];
        int pos = S.lbase[bkt] + (i - S.lpre[bkt]);
        if (pos < CAPB) {
            adjB[(size_t)bkt * CAPB + pos] = vv;
        } else {
            int oi = atomicAdd(ovfCnt, 1);
            ovf[oi] = make_int4(vv.x, vv.y, bkt, 0);
        }
    }
}

// ---------------------------------------------------------------------------
// gather phase body (r7-verified 4-deep): counting-sort bucket slice into
// LDS node-grouped; each HALF-WAVE owns a node with 4 proj loads in flight;
// REGISTER accumulation (r5/r6: LDS-atomic accumulate ~10x slower).
// ---------------------------------------------------------------------------
__device__ inline void gather_bucket(GaLds& S, int b,
        const int2* __restrict__ adjB, const int* __restrict__ cursor,
        const int* __restrict__ ovfCnt, const int4* __restrict__ ovf,
        const unsigned* __restrict__ projU, float* __restrict__ out, int N) {
    int t = threadIdx.x;
    int total = cursor[b];
    int m = min(total, CAPB);
    const int2* base = adjB + (size_t)b * CAPB;

    if (t < NPB) { S.cnt[t] = 0; S.fill[t] = 0; }
    if (t == 0) S.sOvf = *ovfCnt;
    __syncthreads();

    int2 r[GQ];
#pragma unroll
    for (int q = 0; q < GQ; ++q) {
        int e = t + q * BT;
        if (e < m) {
            int2 a = base[e];
            r[q] = a;
            atomicAdd(&S.cnt[((unsigned)a.x) >> 20], 1);
        }
    }
    __syncthreads();
    if (t < NPB) S.pre[t] = S.cnt[t];
    __syncthreads();
    for (int st = 1; st < NPB; st <<= 1) {
        int v = (t < NPB && t >= st) ? S.pre[t - st] : 0;
        __syncthreads();
        if (t < NPB) S.pre[t] += v;
        __syncthreads();
    }
#pragma unroll
    for (int q = 0; q < GQ; ++q) {
        int e = t + q * BT;
        if (e < m) {
            int2 a = r[q];
            int dL = ((unsigned)a.x) >> 20;
            int pos = ((dL == 0) ? 0 : S.pre[dL - 1]) + atomicAdd(&S.fill[dL], 1);
            S.ladj[pos] = make_int2(a.x & 0xFFFFF, a.y);
        }
    }
    __syncthreads();

    int wave = t >> 6;
    int lane = t & 63;
    int half = lane >> 5;
    int k = lane & 31;

#pragma unroll 1
    for (int i = 0; i < 8; ++i) {            // 2 nodes per wave-iter
        int dL = wave * 16 + i * 2 + half;
        int node = b * NPB + dL;
        if (node < N) {
            int rb = (dL == 0) ? 0 : S.pre[dL - 1];
            int re = S.pre[dL];
            float2 accA = make_float2(0.f, 0.f);
            float2 accB = make_float2(0.f, 0.f);
            int j = rb;
            for (; j + 3 < re; j += 4) {
                int2 a0 = S.ladj[j];
                int2 a1 = S.ladj[j + 1];
                int2 a2 = S.ladj[j + 2];
                int2 a3 = S.ladj[j + 3];
                unsigned p0 = projU[(size_t)a0.x * 32 + k];
                unsigned p1 = projU[(size_t)a1.x * 32 + k];
                unsigned p2 = projU[(size_t)a2.x * 32 + k];
                unsigned p3 = projU[(size_t)a3.x * 32 + k];
                float w0 = __int_as_float(a0.y), w1 = __int_as_float(a1.y);
                float w2 = __int_as_float(a2.y), w3 = __int_as_float(a3.y);
                accA.x += w0 * __uint_as_float(p0 << 16);
                accA.y += w0 * __uint_as_float(p0 & 0xFFFF0000u);
                accB.x += w1 * __uint_as_float(p1 << 16);
                accB.y += w1 * __uint_as_float(p1 & 0xFFFF0000u);
                accA.x += w2 * __uint_as_float(p2 << 16);
                accA.y += w2 * __uint_as_float(p2 & 0xFFFF0000u);
                accB.x += w3 * __uint_as_float(p3 << 16);
                accB.y += w3 * __uint_as_float(p3 & 0xFFFF0000u);
            }
            for (; j < re; ++j) {
                int2 a0 = S.ladj[j];
                float w0 = __int_as_float(a0.y);
                unsigned p0 = projU[(size_t)a0.x * 32 + k];
                accA.x += w0 * __uint_as_float(p0 << 16);
                accA.y += w0 * __uint_as_float(p0 & 0xFFFF0000u);
            }
            float2 acc = make_float2(accA.x + accB.x, accA.y + accB.y);
            *(float2*)&out[(size_t)node * D + 2 * k] = acc;
        }
    }

    if (S.sOvf > 0) {                         // insurance path, never hot
        __syncthreads();
        for (int e = t; e < S.sOvf; e += BT) {
            int4 o = ovf[e];
            if (o.z != b) continue;
            int dL = ((unsigned)o.x) >> 20;
            int node = b * NPB + dL;
            if (node >= N) continue;
            float wgt = __int_as_float(o.y);
            int s = o.x & 0xFFFFF;
            for (int d2 = 0; d2 < D / 2; ++d2) {
                unsigned p = projU[(size_t)s * 32 + d2];
                atomicAdd(&out[(size_t)node * D + 2 * d2],     wgt * __uint_as_float(p << 16));
                atomicAdd(&out[(size_t)node * D + 2 * d2 + 1], wgt * __uint_as_float(p & 0xFFFF0000u));
            }
        }
    }
}

// ---------------------------------------------------------------------------
// cooperative fused pipeline: per block {gemm tiles -> flag-wait -> scatter
// chunk} -> grid.sync -> {gather buckets}. One launch, one grid-wide sync;
// early-finishing blocks drift from gemm into scatter (natural overlap,
// phases stay homogeneous per block — avoids r3's static-mix LDS conflicts).
// ---------------------------------------------------------------------------
struct P {
    const int* src; const int* dst; const float* w;
    const float* data; const float* theta;
    unsigned short* proj16; int2* adjB; int4* ovf;
    int* cursor; int* ovfCnt; int* flag; float* out;
    int E, B, N, nTiles;
};

__global__ __launch_bounds__(BT, 6) void fused_pipeline_kernel(P p) {
    __shared__ union { GmLds gm; ScLds sc; GaLds ga; } sm;
    int t = threadIdx.x;
    int bid = blockIdx.x;
    int nblk = gridDim.x;

    // P0: block 0 zeroes cursor[0..B-1] + ovfCnt (=cursor[B]), releases flag.
    if (bid == 0) {
        for (int i = t; i <= p.B; i += BT) p.cursor[i] = 0;
        __syncthreads();
        if (t == 0)
            __hip_atomic_store(p.flag, MAGIC, __ATOMIC_RELEASE, __HIP_MEMORY_SCOPE_AGENT);
    }

    // P1: gemm tiles (grid-stride)
    gemm_theta(sm.gm, p.theta, t);
    for (int tile = bid; tile < p.nTiles; tile += nblk) {
        __syncthreads();                      // protect at[]/th across iters
        gemm_tile(sm.gm, p.data, p.proj16, tile * 64, p.N, t);
    }

    // P1.5: ensure cursors zeroed (long since done; spin is ~0)
    if (t == 0)
        while (__hip_atomic_load(p.flag, __ATOMIC_ACQUIRE, __HIP_MEMORY_SCOPE_AGENT) != MAGIC) {}
    __syncthreads();                          // also fences sm.gm readers

    // P2: scatter chunk
    scatter_body(sm.sc, p.src, p.dst, p.w, p.cursor, p.ovfCnt, p.ovf,
                 p.adjB, p.E, p.B, bid, nblk);

    // P3: make adjB/ovf/cursor/proj16 visible, then grid-wide barrier
    __threadfence();
    cg::this_grid().sync();

    // P4: gather buckets (grid-stride)
    for (int b = bid; b < p.B; b += nblk)
        gather_bucket(sm.ga, b, p.adjB, p.cursor, p.ovfCnt, p.ovf,
                      (const unsigned*)p.proj16, p.out, p.N);
}

// ---------------------------------------------------------------------------
// non-cooperative fallback path (r8-proven 3-kernel sequence)
// ---------------------------------------------------------------------------
__global__ __launch_bounds__(BT, 4) void rowgemm_bf16_kernel(
        const float* __restrict__ A, const float* __restrict__ theta,
        unsigned short* __restrict__ proj16, int* __restrict__ cursor,
        int nCur, int N) {
    __shared__ GmLds S;
    int t = threadIdx.x;
    if (blockIdx.x == 0)
        for (int i = t; i < nCur; i += BT) cursor[i] = 0;
    gemm_theta(S, theta, t);
    __syncthreads();
    gemm_tile(S, A, proj16, blockIdx.x * 64, N, t);
}

__global__ __launch_bounds__(BT) void bucket_scatter_kernel(
        const int* __restrict__ src, const int* __restrict__ dst,
        const float* __restrict__ w, int* __restrict__ cursor,
        int* __restrict__ ovfCnt, int4* __restrict__ ovf,
        int2* __restrict__ adjB, int E, int B) {
    __shared__ ScLds S;
    scatter_body(S, src, dst, w, cursor, ovfCnt, ovf, adjB, E, B,
                 blockIdx.x, gridDim.x);
}

__global__ __launch_bounds__(BT) void sort_gather_kernel(
        const int2* __restrict__ adjB, const int* __restrict__ cursor,
        const int* __restrict__ ovfCnt, const int4* __restrict__ ovf,
        const unsigned* __restrict__ projU, float* __restrict__ out, int N) {
    __shared__ GaLds S;
    gather_bucket(S, blockIdx.x, adjB, cursor, ovfCnt, ovf, projU, out, N);
}

// ---------------------------------------------------------------------------
// last-resort fallback (atomic scatter + fp32 row GEMM) if ws/shape fail
// ---------------------------------------------------------------------------
__global__ void zero_f4_kernel(float4* __restrict__ p, int n4) {
    int i = blockIdx.x * blockDim.x + threadIdx.x;
    if (i < n4) p[i] = make_float4(0.f, 0.f, 0.f, 0.f);
}

__global__ void scatter_kernel(const int* __restrict__ src, const int* __restrict__ dst,
                               const float* __restrict__ w, const float* __restrict__ data,
                               float* __restrict__ agg, int E) {
    int tid = blockIdx.x * blockDim.x + threadIdx.x;
    int e = tid >> 6;
    int d = tid & 63;
    if (e >= E) return;
    float val = w[e] * data[(size_t)src[e] * D + d];
    atomicAdd(&agg[(size_t)dst[e] * D + d], val);
}

__global__ __launch_bounds__(256, 4) void rowgemm_f32_kernel(const float* __restrict__ A,
                                                             const float* __restrict__ theta,
                                                             float* __restrict__ out, int N) {
    __shared__ float th[D * D];
    __shared__ float at[D][68];
    int t = threadIdx.x;
    int rowBase = blockIdx.x * 64;
#pragma unroll
    for (int i = 0; i < 4; ++i) {
        int f = t + i * 256;
        ((float4*)th)[f] = ((const float4*)theta)[f];
    }
#pragma unroll
    for (int i = 0; i < 4; ++i) {
        int f = t + i * 256;
        int row = f >> 4;
        int kv = f & 15;
        float4 v = make_float4(0.f, 0.f, 0.f, 0.f);
        if (rowBase + row < N) v = *(const float4*)&A[(size_t)(rowBase + row) * D + kv * 4];
        at[kv * 4 + 0][row] = v.x;
        at[kv * 4 + 1][row] = v.y;
        at[kv * 4 + 2][row] = v.z;
        at[kv * 4 + 3][row] = v.w;
    }
    __syncthreads();
    int c0 = (t & 15) * 4;
    int r0 = (t >> 4) * 4;
    float4 acc0 = make_float4(0.f, 0.f, 0.f, 0.f);
    float4 acc1 = acc0, acc2 = acc0, acc3 = acc0;
#pragma unroll 16
    for (int kk = 0; kk < D; ++kk) {
        float4 bv = *(const float4*)&th[kk * D + c0];
        float4 av = *(const float4*)&at[kk][r0];
        acc0.x += av.x * bv.x; acc0.y += av.x * bv.y; acc0.z += av.x * bv.z; acc0.w += av.x * bv.w;
        acc1.x += av.y * bv.x; acc1.y += av.y * bv.y; acc1.z += av.y * bv.z; acc1.w += av.y * bv.w;
        acc2.x += av.z * bv.x; acc2.y += av.z * bv.y; acc2.z += av.z * bv.z; acc2.w += av.z * bv.w;
        acc3.x += av.w * bv.x; acc3.y += av.w * bv.y; acc3.z += av.w * bv.z; acc3.w += av.w * bv.w;
    }
    float4 accs[4] = {acc0, acc1, acc2, acc3};
#pragma unroll
    for (int i = 0; i < 4; ++i) {
        int r = rowBase + r0 + i;
        if (r < N) *(float4*)&out[(size_t)r * D + c0] = accs[i];
    }
}

extern "C" void kernel_launch(void* const* d_in, const int* in_sizes, int n_in,
                              void* d_out, int out_size, void* d_ws, size_t ws_size,
                              hipStream_t stream) {
    const int*   src   = (const int*)d_in[0];
    const int*   dst   = (const int*)d_in[1];
    const float* w     = (const float*)d_in[2];
    const float* data  = (const float*)d_in[3];
    const float* theta = (const float*)d_in[4];
    const int E = in_sizes[0];
    const int N = in_sizes[3] / D;
    float* out = (float*)d_out;

    const int B = (N + NPB - 1) / NPB;

    // ws layout: proj16 | adjB (B*CAPB int2) | ovf (E int4) |
    //            cursor[B] | ovfCnt | flag
    size_t projBytes = (size_t)N * D * 2;
    size_t adjBytes  = (size_t)B * CAPB * 8;
    size_t ovfBytes  = (size_t)E * 16;
    size_t need = projBytes + adjBytes + ovfBytes + ((size_t)B + 8) * 4 + 256;
    int coopChunk = (E + GRIDC - 1) / GRIDC;

    if (ws_size >= need && N < (1 << 20) && B <= MAXB && coopChunk <= CHUNK_MAX) {
        unsigned short* proj16 = (unsigned short*)d_ws;
        int2* adjB   = (int2*)((char*)d_ws + projBytes);
        int4* ovf    = (int4*)((char*)d_ws + projBytes + adjBytes);
        int*  cursor = (int*)((char*)d_ws + projBytes + adjBytes + ovfBytes);
        int*  ovfCnt = cursor + B;
        int*  flag   = ovfCnt + 1;

        P p;
        p.src = src; p.dst = dst; p.w = w; p.data = data; p.theta = theta;
        p.proj16 = proj16; p.adjB = adjB; p.ovf = ovf;
        p.cursor = cursor; p.ovfCnt = ovfCnt; p.flag = flag; p.out = out;
        p.E = E; p.B = B; p.N = N; p.nTiles = (N + 63) / 64;

        void* args[] = { &p };
        hipError_t err = hipLaunchCooperativeKernel(
            reinterpret_cast<void*>(fused_pipeline_kernel),
            dim3(GRIDC), dim3(BT), args, 0, stream);

        if (err != hipSuccess) {
            // r8-proven 3-kernel fallback (same bodies, same layout)
            int gs = (E + CHUNK_MAX - 1) / CHUNK_MAX;
            rowgemm_bf16_kernel<<<(N + 63) / 64, BT, 0, stream>>>(data, theta, proj16,
                                                                  cursor, B + 1, N);
            bucket_scatter_kernel<<<gs, BT, 0, stream>>>(src, dst, w, cursor,
                                                         ovfCnt, ovf, adjB, E, B);
            sort_gather_kernel<<<B, BT, 0, stream>>>(adjB, cursor, ovfCnt, ovf,
                                                     (const unsigned*)proj16, out, N);
        }
    } else {
        float* agg = (float*)d_ws;
        int n4 = (N * D) / 4;
        zero_f4_kernel<<<(n4 + 255) / 256, 256, 0, stream>>>((float4*)agg, n4);
        long long total = (long long)E * D;
        scatter_kernel<<<(int)((total + 255) / 256), 256, 0, stream>>>(src, dst, w, data, agg, E);
        rowgemm_f32_kernel<<<(N + 63) / 64, 256, 0, stream>>>(agg, theta, out, N);
    }
}

// Round 10
// 144.509 us; speedup vs baseline: 3.1740x; 3.1740x over previous
//
#include <hip/hip_runtime.h>

#define D 64
#define NPB 128              // nodes per bucket (dstLocal: 7 bits)
#define NPB_SHIFT 7
#define MAXB 1024            // bound on bucket count B = ceil(N/NPB)
#define SCATTER_T 512
#define CHUNK_MAX 4704       // max edges staged per scatter block (LDS-sized)
#define SCQ 10               // per-thread reg-staged edges (SCQ*512 >= CHUNK_MAX)
#define CAPB 2560            // fixed per-bucket capacity in adjB (mean 1534)
#define GT 512               // sort_gather block size (8 waves)
#define GQ 5                 // per-thread reg-staged bucket entries (GQ*GT >= CAPB)

// round-to-nearest-even fp32 -> bf16 (values are finite/normal here)
__device__ inline unsigned f2bf(float f) {
    unsigned u = __float_as_uint(f);
    return (u + 0x7FFFu + ((u >> 16) & 1u)) >> 16;
}

// ---------------------------------------------------------------------------
// zero helpers (ws is poisoned 0xAA every launch)
// ---------------------------------------------------------------------------
__global__ void zero_i_kernel(int* __restrict__ p, int n) {
    int i = blockIdx.x * blockDim.x + threadIdx.x;
    if (i < n) p[i] = 0;
}
__global__ void zero_f4_kernel(float4* __restrict__ p, int n4) {
    int i = blockIdx.x * blockDim.x + threadIdx.x;
    if (i < n4) p[i] = make_float4(0.f, 0.f, 0.f, 0.f);
}

// ---------------------------------------------------------------------------
// bucket scatter (r7-proven verbatim): reg-stage edges -> LDS chunk
// histogram -> local excl scan -> reserve per-bucket ranges from cursors ->
// LDS counting sort -> coalesced write-out in ~48B runs. Overflow past CAPB
// -> ovf list (cold). Packing: x = src | dstLocal<<20, y = w bits.
// ---------------------------------------------------------------------------
__global__ __launch_bounds__(SCATTER_T) void bucket_scatter_kernel(
        const int* __restrict__ src, const int* __restrict__ dst,
        const float* __restrict__ w, int* __restrict__ cursor,
        int* __restrict__ ovfCnt, int4* __restrict__ ovf,
        int2* __restrict__ adjB, int E, int B) {
    __shared__ int lc[MAXB];
    __shared__ int lpre[MAXB];
    __shared__ int lbase[MAXB];
    __shared__ int lfill[MAXB];
    __shared__ int sums[SCATTER_T];
    __shared__ unsigned short sb[CHUNK_MAX];
    __shared__ int2 stage[CHUNK_MAX];

    int t = threadIdx.x;
    int chunk = (E + gridDim.x - 1) / gridDim.x;   // <= CHUNK_MAX by host calc
    int lo = blockIdx.x * chunk, hi = min(lo + chunk, E);
    int n = hi - lo;
    if (n <= 0) return;

    for (int i = t; i < MAXB; i += SCATTER_T) { lc[i] = 0; lfill[i] = 0; }

    // reg-stage this thread's edges (one global pass over dst/src/w)
    int rd[SCQ]; int rs[SCQ]; float rw[SCQ];
#pragma unroll
    for (int q = 0; q < SCQ; ++q) {
        int e = lo + t + q * SCATTER_T;
        bool v = e < hi;
        rd[q] = v ? dst[e] : -1;
        rs[q] = v ? src[e] : 0;
        rw[q] = v ? w[e] : 0.f;
    }
    __syncthreads();

    // A1: chunk histogram
#pragma unroll
    for (int q = 0; q < SCQ; ++q)
        if (rd[q] >= 0) atomicAdd(&lc[rd[q] >> NPB_SHIFT], 1);
    __syncthreads();

    // A2: exclusive scan of lc[0..MAXB) (2/thread + H-S on 512)
    int s0 = lc[2 * t], s1 = lc[2 * t + 1];
    sums[t] = s0 + s1;
    __syncthreads();
    for (int st = 1; st < SCATTER_T; st <<= 1) {
        int v = (t >= st) ? sums[t - st] : 0;
        __syncthreads();
        sums[t] += v;
        __syncthreads();
    }
    int ex = (t == 0) ? 0 : sums[t - 1];
    lpre[2 * t] = ex;
    lpre[2 * t + 1] = ex + s0;
    __syncthreads();

    // A3: reserve per-bucket ranges (1 global atomic per nonempty bucket)
    for (int i = t; i < B; i += SCATTER_T) {
        int c = lc[i];
        lbase[i] = c ? atomicAdd(&cursor[i], c) : 0;
    }
    __syncthreads();

    // B: place into locally-sorted LDS slots
#pragma unroll
    for (int q = 0; q < SCQ; ++q) {
        int d = rd[q];
        if (d >= 0) {
            int bkt = d >> NPB_SHIFT;
            int i = lpre[bkt] + atomicAdd(&lfill[bkt], 1);
            stage[i] = make_int2(rs[q] | ((d & (NPB - 1)) << 20),
                                 __float_as_int(rw[q]));
            sb[i] = (unsigned short)bkt;
        }
    }
    __syncthreads();

    // C: coalesced write-out in locally-sorted order
    for (int i = t; i < n; i += SCATTER_T) {
        int bkt = sb[i];
        int2 v = stage[i];
        int pos = lbase[bkt] + (i - lpre[bkt]);
        if (pos < CAPB) {
            adjB[(size_t)bkt * CAPB + pos] = v;
        } else {                               // cold: bucket overflow
            int oi = atomicAdd(ovfCnt, 1);
            ovf[oi] = make_int4(v.x, v.y, bkt, 0);
        }
    }
}

// ---------------------------------------------------------------------------
// fused sort+gather: preamble r7-verbatim (single global pass reg-stage +
// histogram, scan, node-grouped LDS placement). Gather loop CHANGED: each
// half-wave still owns a node, but its two 16-lane SUB-HALVES take even/odd
// edges with uint2 (8B) proj loads — lane kk owns dims {4kk..4kk+3}. One
// wave VMEM instr now covers 4 edges (512B) vs 2 (256B): half the VMEM
// instructions and loop iterations at identical bytes/MLP/VALU. Combine via
// shfl_xor(16); sub==0 lanes store float4 (256B/node, coalesced).
// REGISTER accumulation (r5/r6: LDS-atomic accumulate ~10x slower).
// ---------------------------------------------------------------------------
__global__ __launch_bounds__(GT) void sort_gather_kernel(
        const int2* __restrict__ adjB, const int* __restrict__ cursor,
        const int* __restrict__ ovfCnt, const int4* __restrict__ ovf,
        const unsigned* __restrict__ projU, float* __restrict__ out, int N) {
    __shared__ int cnt[NPB];
    __shared__ int pre[NPB];
    __shared__ int fill[NPB];
    __shared__ int2 ladj[CAPB];
    __shared__ int sOvf;

    int b = blockIdx.x;
    int t = threadIdx.x;
    int total = cursor[b];
    int m = min(total, CAPB);
    const int2* base = adjB + (size_t)b * CAPB;

    if (t < NPB) { cnt[t] = 0; fill[t] = 0; }
    if (t == 0) sOvf = *ovfCnt;
    __syncthreads();

    // single global pass: reg-stage + histogram
    int2 r[GQ];
#pragma unroll
    for (int q = 0; q < GQ; ++q) {
        int e = t + q * GT;
        if (e < m) {
            int2 a = base[e];
            r[q] = a;
            atomicAdd(&cnt[((unsigned)a.x) >> 20], 1);
        }
    }
    __syncthreads();
    if (t < NPB) pre[t] = cnt[t];
    __syncthreads();
    for (int st = 1; st < NPB; st <<= 1) {
        int v = (t < NPB && t >= st) ? pre[t - st] : 0;
        __syncthreads();
        if (t < NPB) pre[t] += v;
        __syncthreads();
    }
    // place node-grouped into LDS from registers
#pragma unroll
    for (int q = 0; q < GQ; ++q) {
        int e = t + q * GT;
        if (e < m) {
            int2 a = r[q];
            int dL = ((unsigned)a.x) >> 20;
            int pos = ((dL == 0) ? 0 : pre[dL - 1]) + atomicAdd(&fill[dL], 1);
            ladj[pos] = make_int2(a.x & 0xFFFFF, a.y);
        }
    }
    __syncthreads();

    int wave = t >> 6;          // 0..7
    int lane = t & 63;
    int half = lane >> 5;       // half-wave owns a node
    int sub  = (lane >> 4) & 1; // sub-half: even/odd edge parity
    int kk   = lane & 15;       // lane owns dims {4kk..4kk+3}

#pragma unroll 1
    for (int i = 0; i < 8; ++i) {            // 2 nodes per wave-iter
        int dL = wave * 16 + i * 2 + half;
        int node = b * NPB + dL;
        if (node < N) {
            int rb = (dL == 0) ? 0 : pre[dL - 1];
            int re = pre[dL];
            float4 acc = make_float4(0.f, 0.f, 0.f, 0.f);
            int j = rb + sub;
            for (; j + 2 < re; j += 4) {     // 2 uint2 loads in flight / lane
                int2 a0 = ladj[j];
                int2 a1 = ladj[j + 2];
                uint2 p0 = *(const uint2*)&projU[(size_t)a0.x * 32 + 2 * kk];
                uint2 p1 = *(const uint2*)&projU[(size_t)a1.x * 32 + 2 * kk];
                float w0 = __int_as_float(a0.y);
                float w1 = __int_as_float(a1.y);
                acc.x += w0 * __uint_as_float(p0.x << 16);
                acc.y += w0 * __uint_as_float(p0.x & 0xFFFF0000u);
                acc.z += w0 * __uint_as_float(p0.y << 16);
                acc.w += w0 * __uint_as_float(p0.y & 0xFFFF0000u);
                acc.x += w1 * __uint_as_float(p1.x << 16);
                acc.y += w1 * __uint_as_float(p1.x & 0xFFFF0000u);
                acc.z += w1 * __uint_as_float(p1.y << 16);
                acc.w += w1 * __uint_as_float(p1.y & 0xFFFF0000u);
            }
            if (j < re) {                    // parity tail (<=1 per sub)
                int2 a0 = ladj[j];
                uint2 p0 = *(const uint2*)&projU[(size_t)a0.x * 32 + 2 * kk];
                float w0 = __int_as_float(a0.y);
                acc.x += w0 * __uint_as_float(p0.x << 16);
                acc.y += w0 * __uint_as_float(p0.x & 0xFFFF0000u);
                acc.z += w0 * __uint_as_float(p0.y << 16);
                acc.w += w0 * __uint_as_float(p0.y & 0xFFFF0000u);
            }
            // combine even/odd sub-halves (lane^16 stays inside the half)
            acc.x += __shfl(acc.x, lane ^ 16, 64);
            acc.y += __shfl(acc.y, lane ^ 16, 64);
            acc.z += __shfl(acc.z, lane ^ 16, 64);
            acc.w += __shfl(acc.w, lane ^ 16, 64);
            if (sub == 0)                    // 16 lanes x 16B = 256B/node
                *(float4*)&out[(size_t)node * D + 4 * kk] = acc;
        }
    }

    if (sOvf > 0) {                           // insurance path, never hot
        __syncthreads();                      // order our stores before atomics
        for (int e = t; e < sOvf; e += GT) {
            int4 o = ovf[e];
            if (o.z != b) continue;
            int dL = ((unsigned)o.x) >> 20;
            int node = b * NPB + dL;
            if (node >= N) continue;
            float wgt = __int_as_float(o.y);
            int s = o.x & 0xFFFFF;
            for (int d2 = 0; d2 < D / 2; ++d2) {
                unsigned p = projU[(size_t)s * 32 + d2];
                atomicAdd(&out[(size_t)node * D + 2 * d2],     wgt * __uint_as_float(p << 16));
                atomicAdd(&out[(size_t)node * D + 2 * d2 + 1], wgt * __uint_as_float(p & 0xFFFF0000u));
            }
        }
    }
}

// ---------------------------------------------------------------------------
// Tiled row GEMM -> bf16 packed proj (r2/r7-proven, adjacent-pair words:
// word j of a row = (bf16 col 2j, bf16 col 2j+1)). Block = 64 rows; A staged
// transposed in LDS; theta in LDS; thread computes 4x4 block.
// __launch_bounds__(256,4): cap VGPR at 128. unroll 16 keeps ILP in cap.
// ---------------------------------------------------------------------------
__global__ __launch_bounds__(256, 4) void rowgemm_bf16_kernel(const float* __restrict__ A,
                                                              const float* __restrict__ theta,
                                                              unsigned short* __restrict__ proj16,
                                                              int N) {
    __shared__ float th[D * D];
    __shared__ float at[D][68];
    int t = threadIdx.x;
    int rowBase = blockIdx.x * 64;

#pragma unroll
    for (int i = 0; i < 4; ++i) {
        int f = t + i * 256;
        ((float4*)th)[f] = ((const float4*)theta)[f];
    }
#pragma unroll
    for (int i = 0; i < 4; ++i) {
        int f = t + i * 256;
        int row = f >> 4;
        int kv = f & 15;
        float4 v = make_float4(0.f, 0.f, 0.f, 0.f);
        if (rowBase + row < N) v = *(const float4*)&A[(size_t)(rowBase + row) * D + kv * 4];
        at[kv * 4 + 0][row] = v.x;
        at[kv * 4 + 1][row] = v.y;
        at[kv * 4 + 2][row] = v.z;
        at[kv * 4 + 3][row] = v.w;
    }
    __syncthreads();

    int c0 = (t & 15) * 4;
    int r0 = (t >> 4) * 4;
    float4 acc0 = make_float4(0.f, 0.f, 0.f, 0.f);
    float4 acc1 = acc0, acc2 = acc0, acc3 = acc0;

#pragma unroll 16
    for (int k = 0; k < D; ++k) {
        float4 bv = *(const float4*)&th[k * D + c0];
        float4 av = *(const float4*)&at[k][r0];
        acc0.x += av.x * bv.x; acc0.y += av.x * bv.y; acc0.z += av.x * bv.z; acc0.w += av.x * bv.w;
        acc1.x += av.y * bv.x; acc1.y += av.y * bv.y; acc1.z += av.y * bv.z; acc1.w += av.y * bv.w;
        acc2.x += av.z * bv.x; acc2.y += av.z * bv.y; acc2.z += av.z * bv.z; acc2.w += av.z * bv.w;
        acc3.x += av.w * bv.x; acc3.y += av.w * bv.y; acc3.z += av.w * bv.z; acc3.w += av.w * bv.w;
    }

    float4 accs[4] = {acc0, acc1, acc2, acc3};
#pragma unroll
    for (int i = 0; i < 4; ++i) {
        int r = rowBase + r0 + i;
        if (r < N) {
            unsigned lo = f2bf(accs[i].x) | (f2bf(accs[i].y) << 16);
            unsigned hi = f2bf(accs[i].z) | (f2bf(accs[i].w) << 16);
            *(uint2*)&proj16[(size_t)r * D + c0] = make_uint2(lo, hi);
        }
    }
}

// ---------------------------------------------------------------------------
// fallback path (atomic scatter + fp32 row GEMM) if ws/shape checks fail
// ---------------------------------------------------------------------------
__global__ void scatter_kernel(const int* __restrict__ src, const int* __restrict__ dst,
                               const float* __restrict__ w, const float* __restrict__ data,
                               float* __restrict__ agg, int E) {
    int tid = blockIdx.x * blockDim.x + threadIdx.x;
    int e = tid >> 6;
    int d = tid & 63;
    if (e >= E) return;
    float val = w[e] * data[(size_t)src[e] * D + d];
    atomicAdd(&agg[(size_t)dst[e] * D + d], val);
}

__global__ __launch_bounds__(256, 4) void rowgemm_f32_kernel(const float* __restrict__ A,
                                                             const float* __restrict__ theta,
                                                             float* __restrict__ out, int N) {
    __shared__ float th[D * D];
    __shared__ float at[D][68];
    int t = threadIdx.x;
    int rowBase = blockIdx.x * 64;
#pragma unroll
    for (int i = 0; i < 4; ++i) {
        int f = t + i * 256;
        ((float4*)th)[f] = ((const float4*)theta)[f];
    }
#pragma unroll
    for (int i = 0; i < 4; ++i) {
        int f = t + i * 256;
        int row = f >> 4;
        int kv = f & 15;
        float4 v = make_float4(0.f, 0.f, 0.f, 0.f);
        if (rowBase + row < N) v = *(const float4*)&A[(size_t)(rowBase + row) * D + kv * 4];
        at[kv * 4 + 0][row] = v.x;
        at[kv * 4 + 1][row] = v.y;
        at[kv * 4 + 2][row] = v.z;
        at[kv * 4 + 3][row] = v.w;
    }
    __syncthreads();
    int c0 = (t & 15) * 4;
    int r0 = (t >> 4) * 4;
    float4 acc0 = make_float4(0.f, 0.f, 0.f, 0.f);
    float4 acc1 = acc0, acc2 = acc0, acc3 = acc0;
#pragma unroll 16
    for (int kk = 0; kk < D; ++kk) {
        float4 bv = *(const float4*)&th[kk * D + c0];
        float4 av = *(const float4*)&at[kk][r0];
        acc0.x += av.x * bv.x; acc0.y += av.x * bv.y; acc0.z += av.x * bv.z; acc0.w += av.x * bv.w;
        acc1.x += av.y * bv.x; acc1.y += av.y * bv.y; acc1.z += av.y * bv.z; acc1.w += av.y * bv.w;
        acc2.x += av.z * bv.x; acc2.y += av.z * bv.y; acc2.z += av.z * bv.z; acc2.w += av.z * bv.w;
        acc3.x += av.w * bv.x; acc3.y += av.w * bv.y; acc3.z += av.w * bv.z; acc3.w += av.w * bv.w;
    }
    float4 accs[4] = {acc0, acc1, acc2, acc3};
#pragma unroll
    for (int i = 0; i < 4; ++i) {
        int r = rowBase + r0 + i;
        if (r < N) *(float4*)&out[(size_t)r * D + c0] = accs[i];
    }
}

extern "C" void kernel_launch(void* const* d_in, const int* in_sizes, int n_in,
                              void* d_out, int out_size, void* d_ws, size_t ws_size,
                              hipStream_t stream) {
    const int*   src   = (const int*)d_in[0];
    const int*   dst   = (const int*)d_in[1];
    const float* w     = (const float*)d_in[2];
    const float* data  = (const float*)d_in[3];
    const float* theta = (const float*)d_in[4];
    const int E = in_sizes[0];
    const int N = in_sizes[3] / D;
    float* out = (float*)d_out;

    const int B = (N + NPB - 1) / NPB;

    // ws layout: proj16 (bf16, adjacent-pair words) | adjB (B*CAPB int2) |
    //            ovf (E int4) | cursor[B] | ovfCnt
    size_t projBytes = (size_t)N * D * 2;
    size_t adjBytes  = (size_t)B * CAPB * 8;
    size_t ovfBytes  = (size_t)E * 16;
    size_t need = projBytes + adjBytes + ovfBytes + ((size_t)B + 1) * 4 + 256;

    if (ws_size >= need && N < (1 << 20) && B <= MAXB) {
        unsigned short* proj16 = (unsigned short*)d_ws;
        int2* adjB   = (int2*)((char*)d_ws + projBytes);
        int4* ovf    = (int4*)((char*)d_ws + projBytes + adjBytes);
        int*  cursor = (int*)((char*)d_ws + projBytes + adjBytes + ovfBytes);
        int*  ovfCnt = cursor + B;

        int gs = (E + CHUNK_MAX - 1) / CHUNK_MAX;  // chunk <= CHUNK_MAX

        zero_i_kernel<<<(B + 1 + 255) / 256, 256, 0, stream>>>(cursor, B + 1);
        bucket_scatter_kernel<<<gs, SCATTER_T, 0, stream>>>(src, dst, w, cursor,
                                                            ovfCnt, ovf, adjB, E, B);
        rowgemm_bf16_kernel<<<(N + 63) / 64, 256, 0, stream>>>(data, theta, proj16, N);
        sort_gather_kernel<<<B, GT, 0, stream>>>(adjB, cursor, ovfCnt, ovf,
                                                 (const unsigned*)proj16, out, N);
    } else {
        float* agg = (float*)d_ws;
        int n4 = (N * D) / 4;
        zero_f4_kernel<<<(n4 + 255) / 256, 256, 0, stream>>>((float4*)agg, n4);
        long long total = (long long)E * D;
        scatter_kernel<<<(int)((total + 255) / 256), 256, 0, stream>>>(src, dst, w, data, agg, E);
        rowgemm_f32_kernel<<<(N + 63) / 64, 256, 0, stream>>>(agg, theta, out, N);
    }
}